// Round 18
// baseline (416.410 us; speedup 1.0000x reference)
//
#include <hip/hip_runtime.h>
#include <cstdint>
#include <cstddef>

#define NN 100000
#define NE 1600000
#define DIM 256
#define NA 100352            // NN rounded up
#define NB 98                // buckets of 1024 node ids
#define SCB 512              // scatter blocks
#define EPB (NE / SCB)       // 3125 edges per block (exact)
#define CNT 50176            // NB*SCB = 49*1024 (exact for the scan)

// int-offset layout in ws:
#define CNTD_I 0                      // cnt[bucket][block], dst side
#define CNTS_I CNT                    // src side
#define ROWP_I (2*CNT)                // rowp[NA+16]
#define NDST_I (2*CNT + NA + 16)      // normdst f32[NA]
#define NSRC_I (2*CNT + 2*NA + 16)    // normsrc f32[NA]
#define CSR_I  (2*CNT + 3*NA + 16)    // csr[NE]
#define PAIR_I (CSR_I + NE)           // packed pairs int[NE]
#define SRCV_I (PAIR_I + NE)          // srcv[NE]
#define HS_B   ((size_t)(SRCV_I + NE) * 4)
#define WT_B   (HS_B + (size_t)NN*DIM*2)
#define WS_NEED (WT_B + (size_t)DIM*DIM*2)

typedef short bf16x8 __attribute__((ext_vector_type(8)));
typedef float f32x4 __attribute__((ext_vector_type(4)));
typedef unsigned short u16x4 __attribute__((ext_vector_type(4)));

__device__ __forceinline__ float bf2f(unsigned short u) {
    return __uint_as_float(((unsigned)u) << 16);
}
__device__ __forceinline__ unsigned short f2bf(float f) {
    unsigned u = __float_as_uint(f);
    u += 0x7FFF + ((u >> 16) & 1);   // round-to-nearest-even
    return (unsigned short)(u >> 16);
}

// ---- A: per-block LDS histograms -> cnt matrices + h->bf16 convert ---------
// Counts are WRITTEN (not atomically accumulated) -> no memset, no global atomics.
__global__ __launch_bounds__(256) void k_s1(
        const int* __restrict__ src, const int* __restrict__ dst,
        const float* __restrict__ h,
        int* __restrict__ cntD, int* __restrict__ cntS,
        unsigned short* __restrict__ hs) {
    __shared__ int lhd[NB], lhs[NB];
    int tid = threadIdx.x;
    if (tid < NB) { lhd[tid] = 0; lhs[tid] = 0; }
    __syncthreads();
    int e0 = blockIdx.x * EPB, e1 = e0 + EPB;
    for (int e = e0 + tid; e < e1; e += 256) {
        atomicAdd(&lhd[dst[e] >> 10], 1);   // LDS
        atomicAdd(&lhs[src[e] >> 10], 1);   // LDS
    }
    // h -> raw bf16 (independent; overlaps)
    int gid = blockIdx.x * 256 + tid;
    int gstride = gridDim.x * 256;
    for (int i = gid; i < NN * (DIM / 4); i += gstride) {
        float4 v = ((const float4*)h)[i];
        u16x4 o;
        o.x = f2bf(v.x);
        o.y = f2bf(v.y);
        o.z = f2bf(v.z);
        o.w = f2bf(v.w);
        ((u16x4*)hs)[i] = o;
    }
    __syncthreads();
    if (tid < NB) {
        cntD[tid * SCB + blockIdx.x] = lhd[tid];   // bucket-major
        cntS[tid * SCB + blockIdx.x] = lhs[tid];
    }
}

// ---- B: exclusive scan of both 50176-int count matrices (1 block) ----------
// After scan, cnt[b*SCB+blk] = global scatter base for block blk's bucket-b edges;
// cnt[b*SCB] = bucket b's base.
__global__ __launch_bounds__(1024) void k_scan(int* __restrict__ cntD,
                                               int* __restrict__ cntS,
                                               int* __restrict__ rowp) {
    __shared__ int tmp[1024];
    __shared__ int carrysh;
    int tid = threadIdx.x;
    for (int side = 0; side < 2; ++side) {
        int* c = side ? cntS : cntD;
        if (tid == 0) carrysh = 0;
        __syncthreads();
        for (int chunk = 0; chunk < CNT / 1024; ++chunk) {   // 49 exact
            int i = chunk * 1024 + tid;
            int x = c[i];
            tmp[tid] = x;
            __syncthreads();
            for (int off = 1; off < 1024; off <<= 1) {
                int v = (tid >= off) ? tmp[tid - off] : 0;
                __syncthreads();
                tmp[tid] += v;
                __syncthreads();
            }
            int incl = tmp[tid];
            int carry = carrysh;
            c[i] = incl - x + carry;
            __syncthreads();
            if (tid == 1023) carrysh = carry + incl;
            __syncthreads();
        }
    }
    if (tid == 0) rowp[NN] = NE;
}

// ---- C: scatter with preloaded exact cursors + weight pack -----------------
// pairs packed: (d&1023)<<17 | s   (s < 2^17)
__global__ __launch_bounds__(256) void k_s2(
        const int* __restrict__ src, const int* __restrict__ dst,
        const float* __restrict__ W,
        const int* __restrict__ cntD, const int* __restrict__ cntS,
        int* __restrict__ pairs, int* __restrict__ srcv,
        unsigned short* __restrict__ wtp) {
    __shared__ int curd[NB], curs[NB];
    int tid = threadIdx.x;
    if (tid < NB) {
        curd[tid] = cntD[tid * SCB + blockIdx.x];
        curs[tid] = cntS[tid * SCB + blockIdx.x];
    }
    __syncthreads();
    int e0 = blockIdx.x * EPB, e1 = e0 + EPB;
    for (int e = e0 + tid; e < e1; e += 256) {
        int d = dst[e], s = src[e];
        int pos = atomicAdd(&curd[d >> 10], 1);    // LDS returning
        pairs[pos] = ((d & 1023) << 17) | s;
        int pos2 = atomicAdd(&curs[s >> 10], 1);
        srcv[pos2] = s;
    }
    int gid = blockIdx.x * 256 + tid;
    if (gid < DIM * DIM) {
        int p = gid;
        int j = p & 7, l = (p >> 3) & 63, t = (p >> 9) & 15, ks = p >> 13;
        wtp[p] = f2bf(W[(ks * 32 + (l >> 4) * 8 + j) * DIM + t * 16 + (l & 15)]);
    }
}

// ---- D: per-bucket fine pass, all LDS-local --------------------------------
__global__ __launch_bounds__(256) void k_fine(
        const int* __restrict__ pairs, const int* __restrict__ srcv,
        const int* __restrict__ cntD, const int* __restrict__ cntS,
        int* __restrict__ rowp, float* __restrict__ normdst,
        float* __restrict__ normsrc, int* __restrict__ csr) {
    __shared__ int fine[1024];
    __shared__ int excl[1024];
    __shared__ int part[256];
    int tid = threadIdx.x;
    if (blockIdx.x >= NB) {                       // ---- src side ----
        int bin = blockIdx.x - NB;
        int lo = bin << 10;
        int ebase = cntS[bin * SCB];
        int eend = (bin == NB - 1) ? NE : cntS[(bin + 1) * SCB];
#pragma unroll
        for (int k = 0; k < 4; ++k) fine[tid * 4 + k] = 0;
        __syncthreads();
        for (int e = ebase + tid; e < eend; e += 256)
            atomicAdd(&fine[srcv[e] - lo], 1);
        __syncthreads();
#pragma unroll
        for (int k = 0; k < 4; ++k) {
            int j = tid * 4 + k;
            int node = lo + j;
            if (node < NN)
                normsrc[node] = rsqrtf(fmaxf((float)fine[j], 1.0f));
        }
        return;
    }
    // ---- dst side ----
    int bin = blockIdx.x;
    int lo = bin << 10;
    int ebase = cntD[bin * SCB];
    int eend = (bin == NB - 1) ? NE : cntD[(bin + 1) * SCB];
#pragma unroll
    for (int k = 0; k < 4; ++k) fine[tid * 4 + k] = 0;
    __syncthreads();
    for (int e = ebase + tid; e < eend; e += 256)
        atomicAdd(&fine[((unsigned)pairs[e]) >> 17], 1);
    __syncthreads();
    int c0 = fine[tid * 4], c1 = fine[tid * 4 + 1];
    int c2 = fine[tid * 4 + 2], c3 = fine[tid * 4 + 3];
    int psum = c0 + c1 + c2 + c3;
    part[tid] = psum;
    __syncthreads();
    for (int off = 1; off < 256; off <<= 1) {
        int v = (tid >= off) ? part[tid - off] : 0;
        __syncthreads();
        part[tid] += v;
        __syncthreads();
    }
    int eb = part[tid] - psum;
    excl[tid * 4] = eb;
    excl[tid * 4 + 1] = eb + c0;
    excl[tid * 4 + 2] = eb + c0 + c1;
    excl[tid * 4 + 3] = eb + c0 + c1 + c2;
#pragma unroll
    for (int k = 0; k < 4; ++k) {
        int j = tid * 4 + k;
        int node = lo + j;
        if (node < NN) {
            rowp[node] = ebase + excl[j];
            normdst[node] = rsqrtf(fmaxf((float)fine[j], 1.0f));
        }
    }
    __syncthreads();
    for (int e = ebase + tid; e < eend; e += 256) {
        int p = pairs[e];
        int r = atomicAdd(&excl[((unsigned)p) >> 17], 1);
        csr[ebase + r] = p & 0x1FFFF;
    }
}

// ---- E: FUSED aggregate + GEMM + bias + ELU (R17-verbatim, proven) ---------
__global__ __launch_bounds__(256) void k_aggemm(const unsigned short* __restrict__ hs,
                                                const int* __restrict__ csr,
                                                const int* __restrict__ rowp,
                                                const float* __restrict__ normdst,
                                                const float* __restrict__ normsrc,
                                                const unsigned short* __restrict__ wtp,
                                                const float* __restrict__ bias,
                                                float* __restrict__ out) {
    __shared__ short As[16][264];
    int wave = threadIdx.x >> 6;
    int lane = threadIdx.x & 63;
    int nb = blockIdx.x * 16;

    for (int i = 0; i < 4; ++i) {
        int r = wave * 4 + i;
        int node = nb + r;
        int e0 = rowp[node], e1 = rowp[node + 1];
        float a0 = 0.f, a1 = 0.f, a2 = 0.f, a3 = 0.f;
        for (int base = e0; base < e1; base += 64) {
            int n = e1 - base;
            if (n > 64) n = 64;
            int idx = base + lane;
            int csrv = (idx < e1) ? csr[idx] : 0;
            int j = 0;
            for (; j + 3 < n; j += 4) {
                int s0 = __builtin_amdgcn_readlane(csrv, j);
                int s1 = __builtin_amdgcn_readlane(csrv, j + 1);
                int s2 = __builtin_amdgcn_readlane(csrv, j + 2);
                int s3 = __builtin_amdgcn_readlane(csrv, j + 3);
                float n0 = normsrc[s0], n1 = normsrc[s1];
                float n2 = normsrc[s2], n3 = normsrc[s3];
                u16x4 u0 = ((const u16x4*)(hs + (size_t)s0 * DIM))[lane];
                u16x4 u1 = ((const u16x4*)(hs + (size_t)s1 * DIM))[lane];
                u16x4 u2 = ((const u16x4*)(hs + (size_t)s2 * DIM))[lane];
                u16x4 u3 = ((const u16x4*)(hs + (size_t)s3 * DIM))[lane];
                a0 = fmaf(bf2f(u0.x), n0, fmaf(bf2f(u1.x), n1,
                     fmaf(bf2f(u2.x), n2, fmaf(bf2f(u3.x), n3, a0))));
                a1 = fmaf(bf2f(u0.y), n0, fmaf(bf2f(u1.y), n1,
                     fmaf(bf2f(u2.y), n2, fmaf(bf2f(u3.y), n3, a1))));
                a2 = fmaf(bf2f(u0.z), n0, fmaf(bf2f(u1.z), n1,
                     fmaf(bf2f(u2.z), n2, fmaf(bf2f(u3.z), n3, a2))));
                a3 = fmaf(bf2f(u0.w), n0, fmaf(bf2f(u1.w), n1,
                     fmaf(bf2f(u2.w), n2, fmaf(bf2f(u3.w), n3, a3))));
            }
            for (; j < n; ++j) {
                int s0 = __builtin_amdgcn_readlane(csrv, j);
                float n0 = normsrc[s0];
                u16x4 u = ((const u16x4*)(hs + (size_t)s0 * DIM))[lane];
                a0 = fmaf(bf2f(u.x), n0, a0);
                a1 = fmaf(bf2f(u.y), n0, a1);
                a2 = fmaf(bf2f(u.z), n0, a2);
                a3 = fmaf(bf2f(u.w), n0, a3);
            }
        }
        float nd = normdst[node];
        u16x4 o;
        o.x = f2bf(a0 * nd);
        o.y = f2bf(a1 * nd);
        o.z = f2bf(a2 * nd);
        o.w = f2bf(a3 * nd);
        *(u16x4*)&As[r][4 * lane] = o;
    }
    __syncthreads();

    const short* B = (const short*)wtp + lane * 8;
    f32x4 acc[4];
#pragma unroll
    for (int tt = 0; tt < 4; ++tt) acc[tt] = (f32x4){0.f, 0.f, 0.f, 0.f};

    int fr = lane & 15;
    int q  = lane >> 4;
    for (int ks = 0; ks < 8; ++ks) {
        bf16x8 a = *(const bf16x8*)&As[fr][ks * 32 + q * 8];
#pragma unroll
        for (int tt = 0; tt < 4; ++tt) {
            int t = wave * 4 + tt;
            bf16x8 b = *(const bf16x8*)(B + (size_t)(ks * 16 + t) * 512);
            acc[tt] = __builtin_amdgcn_mfma_f32_16x16x32_bf16(a, b, acc[tt], 0, 0, 0);
        }
    }

    int rbase = nb + q * 4;
#pragma unroll
    for (int tt = 0; tt < 4; ++tt) {
        int col = wave * 64 + tt * 16 + fr;
        float bv = bias[col];
#pragma unroll
        for (int i = 0; i < 4; ++i) {
            float v = acc[tt][i] + bv;
            v = v > 0.f ? v : expm1f(v);
            __builtin_nontemporal_store(v, &out[(size_t)(rbase + i) * DIM + col]);
        }
    }
}

extern "C" void kernel_launch(void* const* d_in, const int* in_sizes, int n_in,
                              void* d_out, int out_size, void* d_ws, size_t ws_size,
                              hipStream_t stream) {
    const float* h    = (const float*)d_in[0];
    const float* W    = (const float*)d_in[1];
    const float* bias = (const float*)d_in[2];
    const int*   src  = (const int*)d_in[3];
    const int*   dst  = (const int*)d_in[4];
    float* out = (float*)d_out;

    if (ws_size < WS_NEED) return;  // insufficient scratch -> loud failure

    char* w = (char*)d_ws;
    int* bi = (int*)w;
    int* cntD = bi + CNTD_I;
    int* cntS = bi + CNTS_I;
    int* rowp = bi + ROWP_I;
    float* normdst = (float*)(bi + NDST_I);
    float* normsrc = (float*)(bi + NSRC_I);
    int* csr   = bi + CSR_I;
    int* pairs = bi + PAIR_I;
    int* srcv  = bi + SRCV_I;
    unsigned short* hs  = (unsigned short*)(w + HS_B);
    unsigned short* wtp = (unsigned short*)(w + WT_B);

    k_s1<<<SCB, 256, 0, stream>>>(src, dst, h, cntD, cntS, hs);
    k_scan<<<1, 1024, 0, stream>>>(cntD, cntS, rowp);
    k_s2<<<SCB, 256, 0, stream>>>(src, dst, W, cntD, cntS, pairs, srcv, wtp);
    k_fine<<<2 * NB, 256, 0, stream>>>(pairs, srcv, cntD, cntS, rowp, normdst, normsrc, csr);
    k_aggemm<<<NN / 16, 256, 0, stream>>>(hs, csr, rowp, normdst, normsrc, wtp, bias, out);
}

// Round 19
// 259.905 us; speedup vs baseline: 1.6022x; 1.6022x over previous
//
#include <hip/hip_runtime.h>
#include <cstdint>
#include <cstddef>

#define NN 100000
#define NE 1600000
#define DIM 256
#define NA 100352            // NN rounded up
#define NB 98                // buckets of 1024 node ids
#define SCB 512              // scatter blocks
#define EPB (NE / SCB)       // 3125 edges per block (exact)
#define CNT 50176            // NB*SCB

// int-offset layout in ws:
#define CNTD_I 0                      // cnt[bucket][block], dst side
#define CNTS_I CNT                    // src side
#define TOTD_I (2*CNT)                // bucket totals dst [128]
#define TOTS_I (2*CNT + 128)          // bucket totals src [128]
#define BD_I   (2*CNT + 256)          // baseD[99] pad 128
#define BS_I   (2*CNT + 384)          // baseS[99] pad 128
#define ROWP_I (2*CNT + 512)          // rowp[NA+16]
#define NDST_I (ROWP_I + NA + 16)     // normdst f32[NA]
#define NSRC_I (NDST_I + NA)          // normsrc f32[NA]
#define CSR_I  (NSRC_I + NA)          // csr[NE]
#define PAIR_I (CSR_I + NE)           // packed pairs int[NE]
#define SRCV_I (PAIR_I + NE)          // srcv[NE]
#define HS_B   ((size_t)(SRCV_I + NE) * 4)
#define WT_B   (HS_B + (size_t)NN*DIM*2)
#define WS_NEED (WT_B + (size_t)DIM*DIM*2)

typedef short bf16x8 __attribute__((ext_vector_type(8)));
typedef float f32x4 __attribute__((ext_vector_type(4)));
typedef unsigned short u16x4 __attribute__((ext_vector_type(4)));

__device__ __forceinline__ float bf2f(unsigned short u) {
    return __uint_as_float(((unsigned)u) << 16);
}
__device__ __forceinline__ unsigned short f2bf(float f) {
    unsigned u = __float_as_uint(f);
    u += 0x7FFF + ((u >> 16) & 1);   // round-to-nearest-even
    return (unsigned short)(u >> 16);
}

// ---- A: per-block LDS histograms -> cnt matrices + h->bf16 convert ---------
__global__ __launch_bounds__(256) void k_s1(
        const int* __restrict__ src, const int* __restrict__ dst,
        const float* __restrict__ h,
        int* __restrict__ cntD, int* __restrict__ cntS,
        unsigned short* __restrict__ hs) {
    __shared__ int lhd[NB], lhs[NB];
    int tid = threadIdx.x;
    if (tid < NB) { lhd[tid] = 0; lhs[tid] = 0; }
    __syncthreads();
    int e0 = blockIdx.x * EPB, e1 = e0 + EPB;
    for (int e = e0 + tid; e < e1; e += 256) {
        atomicAdd(&lhd[dst[e] >> 10], 1);   // LDS
        atomicAdd(&lhs[src[e] >> 10], 1);   // LDS
    }
    // h -> raw bf16 (independent; overlaps)
    int gid = blockIdx.x * 256 + tid;
    int gstride = gridDim.x * 256;
    for (int i = gid; i < NN * (DIM / 4); i += gstride) {
        float4 v = ((const float4*)h)[i];
        u16x4 o;
        o.x = f2bf(v.x);
        o.y = f2bf(v.y);
        o.z = f2bf(v.z);
        o.w = f2bf(v.w);
        ((u16x4*)hs)[i] = o;
    }
    __syncthreads();
    if (tid < NB) {
        cntD[tid * SCB + blockIdx.x] = lhd[tid];   // bucket-major, written
        cntS[tid * SCB + blockIdx.x] = lhs[tid];
    }
}

// ---- B1: per-bucket exclusive scan of its 512-entry row (in place) ---------
// blocks [0,NB): dst rows; [NB,2NB): src rows. Emits bucket totals.
__global__ __launch_bounds__(256) void k_scanA(
        int* __restrict__ cntD, int* __restrict__ cntS,
        int* __restrict__ totD, int* __restrict__ totS) {
    __shared__ int pair[256];
    int tid = threadIdx.x;
    int side = blockIdx.x >= NB;
    int b = side ? blockIdx.x - NB : blockIdx.x;
    int* c = side ? cntS : cntD;
    int* tot = side ? totS : totD;
    int i0 = b * SCB + tid * 2;
    int x0 = c[i0], x1 = c[i0 + 1];
    int ps = x0 + x1;
    pair[tid] = ps;
    __syncthreads();
    for (int off = 1; off < 256; off <<= 1) {
        int v = (tid >= off) ? pair[tid - off] : 0;
        __syncthreads();
        pair[tid] += v;
        __syncthreads();
    }
    int excl = pair[tid] - ps;     // exclusive over pairs
    c[i0] = excl;
    c[i0 + 1] = excl + x0;
    if (tid == 255) tot[b] = pair[255];
}

// ---- B2: tiny scan of the 98 bucket totals per side -> bases ---------------
__global__ void k_scanB(const int* __restrict__ totD, const int* __restrict__ totS,
                        int* __restrict__ baseD, int* __restrict__ baseS,
                        int* __restrict__ rowp) {
    __shared__ int tmp[128];
    int t = threadIdx.x;
    int x = (t < NB) ? totD[t] : 0;
    tmp[t] = x;
    __syncthreads();
    for (int off = 1; off < 128; off <<= 1) {
        int v = (t >= off) ? tmp[t - off] : 0;
        __syncthreads();
        tmp[t] += v;
        __syncthreads();
    }
    if (t < NB) baseD[t] = tmp[t] - x;
    __syncthreads();
    int y = (t < NB) ? totS[t] : 0;
    tmp[t] = y;
    __syncthreads();
    for (int off = 1; off < 128; off <<= 1) {
        int v = (t >= off) ? tmp[t - off] : 0;
        __syncthreads();
        tmp[t] += v;
        __syncthreads();
    }
    if (t < NB) baseS[t] = tmp[t] - y;
    if (t == 0) {
        baseD[NB] = NE;
        baseS[NB] = NE;
        rowp[NN] = NE;
    }
}

// ---- C: scatter with preloaded exact cursors + weight pack -----------------
// pairs packed: (d&1023)<<17 | s   (s < 2^17)
__global__ __launch_bounds__(256) void k_s2(
        const int* __restrict__ src, const int* __restrict__ dst,
        const float* __restrict__ W,
        const int* __restrict__ cntD, const int* __restrict__ cntS,
        const int* __restrict__ baseD, const int* __restrict__ baseS,
        int* __restrict__ pairs, int* __restrict__ srcv,
        unsigned short* __restrict__ wtp) {
    __shared__ int curd[NB], curs[NB];
    int tid = threadIdx.x;
    if (tid < NB) {
        curd[tid] = baseD[tid] + cntD[tid * SCB + blockIdx.x];
        curs[tid] = baseS[tid] + cntS[tid * SCB + blockIdx.x];
    }
    __syncthreads();
    int e0 = blockIdx.x * EPB, e1 = e0 + EPB;
    for (int e = e0 + tid; e < e1; e += 256) {
        int d = dst[e], s = src[e];
        int pos = atomicAdd(&curd[d >> 10], 1);    // LDS returning
        pairs[pos] = ((d & 1023) << 17) | s;
        int pos2 = atomicAdd(&curs[s >> 10], 1);
        srcv[pos2] = s;
    }
    int gid = blockIdx.x * 256 + tid;
    if (gid < DIM * DIM) {
        int p = gid;
        int j = p & 7, l = (p >> 3) & 63, t = (p >> 9) & 15, ks = p >> 13;
        wtp[p] = f2bf(W[(ks * 32 + (l >> 4) * 8 + j) * DIM + t * 16 + (l & 15)]);
    }
}

// ---- D: per-bucket fine pass, all LDS-local --------------------------------
__global__ __launch_bounds__(256) void k_fine(
        const int* __restrict__ pairs, const int* __restrict__ srcv,
        const int* __restrict__ baseD, const int* __restrict__ baseS,
        int* __restrict__ rowp, float* __restrict__ normdst,
        float* __restrict__ normsrc, int* __restrict__ csr) {
    __shared__ int fine[1024];
    __shared__ int excl[1024];
    __shared__ int part[256];
    int tid = threadIdx.x;
    if (blockIdx.x >= NB) {                       // ---- src side ----
        int bin = blockIdx.x - NB;
        int lo = bin << 10;
        int ebase = baseS[bin], eend = baseS[bin + 1];
#pragma unroll
        for (int k = 0; k < 4; ++k) fine[tid * 4 + k] = 0;
        __syncthreads();
        for (int e = ebase + tid; e < eend; e += 256)
            atomicAdd(&fine[srcv[e] - lo], 1);
        __syncthreads();
#pragma unroll
        for (int k = 0; k < 4; ++k) {
            int j = tid * 4 + k;
            int node = lo + j;
            if (node < NN)
                normsrc[node] = rsqrtf(fmaxf((float)fine[j], 1.0f));
        }
        return;
    }
    // ---- dst side ----
    int bin = blockIdx.x;
    int lo = bin << 10;
    int ebase = baseD[bin], eend = baseD[bin + 1];
#pragma unroll
    for (int k = 0; k < 4; ++k) fine[tid * 4 + k] = 0;
    __syncthreads();
    for (int e = ebase + tid; e < eend; e += 256)
        atomicAdd(&fine[((unsigned)pairs[e]) >> 17], 1);
    __syncthreads();
    int c0 = fine[tid * 4], c1 = fine[tid * 4 + 1];
    int c2 = fine[tid * 4 + 2], c3 = fine[tid * 4 + 3];
    int psum = c0 + c1 + c2 + c3;
    part[tid] = psum;
    __syncthreads();
    for (int off = 1; off < 256; off <<= 1) {
        int v = (tid >= off) ? part[tid - off] : 0;
        __syncthreads();
        part[tid] += v;
        __syncthreads();
    }
    int eb = part[tid] - psum;
    excl[tid * 4] = eb;
    excl[tid * 4 + 1] = eb + c0;
    excl[tid * 4 + 2] = eb + c0 + c1;
    excl[tid * 4 + 3] = eb + c0 + c1 + c2;
#pragma unroll
    for (int k = 0; k < 4; ++k) {
        int j = tid * 4 + k;
        int node = lo + j;
        if (node < NN) {
            rowp[node] = ebase + excl[j];
            normdst[node] = rsqrtf(fmaxf((float)fine[j], 1.0f));
        }
    }
    __syncthreads();
    for (int e = ebase + tid; e < eend; e += 256) {
        int p = pairs[e];
        int r = atomicAdd(&excl[((unsigned)p) >> 17], 1);
        csr[ebase + r] = p & 0x1FFFF;
    }
}

// ---- E: FUSED aggregate + GEMM + bias + ELU (R17-verbatim, proven) ---------
__global__ __launch_bounds__(256) void k_aggemm(const unsigned short* __restrict__ hs,
                                                const int* __restrict__ csr,
                                                const int* __restrict__ rowp,
                                                const float* __restrict__ normdst,
                                                const float* __restrict__ normsrc,
                                                const unsigned short* __restrict__ wtp,
                                                const float* __restrict__ bias,
                                                float* __restrict__ out) {
    __shared__ short As[16][264];
    int wave = threadIdx.x >> 6;
    int lane = threadIdx.x & 63;
    int nb = blockIdx.x * 16;

    for (int i = 0; i < 4; ++i) {
        int r = wave * 4 + i;
        int node = nb + r;
        int e0 = rowp[node], e1 = rowp[node + 1];
        float a0 = 0.f, a1 = 0.f, a2 = 0.f, a3 = 0.f;
        for (int base = e0; base < e1; base += 64) {
            int n = e1 - base;
            if (n > 64) n = 64;
            int idx = base + lane;
            int csrv = (idx < e1) ? csr[idx] : 0;
            int j = 0;
            for (; j + 3 < n; j += 4) {
                int s0 = __builtin_amdgcn_readlane(csrv, j);
                int s1 = __builtin_amdgcn_readlane(csrv, j + 1);
                int s2 = __builtin_amdgcn_readlane(csrv, j + 2);
                int s3 = __builtin_amdgcn_readlane(csrv, j + 3);
                float n0 = normsrc[s0], n1 = normsrc[s1];
                float n2 = normsrc[s2], n3 = normsrc[s3];
                u16x4 u0 = ((const u16x4*)(hs + (size_t)s0 * DIM))[lane];
                u16x4 u1 = ((const u16x4*)(hs + (size_t)s1 * DIM))[lane];
                u16x4 u2 = ((const u16x4*)(hs + (size_t)s2 * DIM))[lane];
                u16x4 u3 = ((const u16x4*)(hs + (size_t)s3 * DIM))[lane];
                a0 = fmaf(bf2f(u0.x), n0, fmaf(bf2f(u1.x), n1,
                     fmaf(bf2f(u2.x), n2, fmaf(bf2f(u3.x), n3, a0))));
                a1 = fmaf(bf2f(u0.y), n0, fmaf(bf2f(u1.y), n1,
                     fmaf(bf2f(u2.y), n2, fmaf(bf2f(u3.y), n3, a1))));
                a2 = fmaf(bf2f(u0.z), n0, fmaf(bf2f(u1.z), n1,
                     fmaf(bf2f(u2.z), n2, fmaf(bf2f(u3.z), n3, a2))));
                a3 = fmaf(bf2f(u0.w), n0, fmaf(bf2f(u1.w), n1,
                     fmaf(bf2f(u2.w), n2, fmaf(bf2f(u3.w), n3, a3))));
            }
            for (; j < n; ++j) {
                int s0 = __builtin_amdgcn_readlane(csrv, j);
                float n0 = normsrc[s0];
                u16x4 u = ((const u16x4*)(hs + (size_t)s0 * DIM))[lane];
                a0 = fmaf(bf2f(u.x), n0, a0);
                a1 = fmaf(bf2f(u.y), n0, a1);
                a2 = fmaf(bf2f(u.z), n0, a2);
                a3 = fmaf(bf2f(u.w), n0, a3);
            }
        }
        float nd = normdst[node];
        u16x4 o;
        o.x = f2bf(a0 * nd);
        o.y = f2bf(a1 * nd);
        o.z = f2bf(a2 * nd);
        o.w = f2bf(a3 * nd);
        *(u16x4*)&As[r][4 * lane] = o;
    }
    __syncthreads();

    const short* B = (const short*)wtp + lane * 8;
    f32x4 acc[4];
#pragma unroll
    for (int tt = 0; tt < 4; ++tt) acc[tt] = (f32x4){0.f, 0.f, 0.f, 0.f};

    int fr = lane & 15;
    int q  = lane >> 4;
    for (int ks = 0; ks < 8; ++ks) {
        bf16x8 a = *(const bf16x8*)&As[fr][ks * 32 + q * 8];
#pragma unroll
        for (int tt = 0; tt < 4; ++tt) {
            int t = wave * 4 + tt;
            bf16x8 b = *(const bf16x8*)(B + (size_t)(ks * 16 + t) * 512);
            acc[tt] = __builtin_amdgcn_mfma_f32_16x16x32_bf16(a, b, acc[tt], 0, 0, 0);
        }
    }

    int rbase = nb + q * 4;
#pragma unroll
    for (int tt = 0; tt < 4; ++tt) {
        int col = wave * 64 + tt * 16 + fr;
        float bv = bias[col];
#pragma unroll
        for (int i = 0; i < 4; ++i) {
            float v = acc[tt][i] + bv;
            v = v > 0.f ? v : expm1f(v);
            __builtin_nontemporal_store(v, &out[(size_t)(rbase + i) * DIM + col]);
        }
    }
}

extern "C" void kernel_launch(void* const* d_in, const int* in_sizes, int n_in,
                              void* d_out, int out_size, void* d_ws, size_t ws_size,
                              hipStream_t stream) {
    const float* h    = (const float*)d_in[0];
    const float* W    = (const float*)d_in[1];
    const float* bias = (const float*)d_in[2];
    const int*   src  = (const int*)d_in[3];
    const int*   dst  = (const int*)d_in[4];
    float* out = (float*)d_out;

    if (ws_size < WS_NEED) return;  // insufficient scratch -> loud failure

    char* w = (char*)d_ws;
    int* bi = (int*)w;
    int* cntD = bi + CNTD_I;
    int* cntS = bi + CNTS_I;
    int* totD = bi + TOTD_I;
    int* totS = bi + TOTS_I;
    int* baseD = bi + BD_I;
    int* baseS = bi + BS_I;
    int* rowp = bi + ROWP_I;
    float* normdst = (float*)(bi + NDST_I);
    float* normsrc = (float*)(bi + NSRC_I);
    int* csr   = bi + CSR_I;
    int* pairs = bi + PAIR_I;
    int* srcv  = bi + SRCV_I;
    unsigned short* hs  = (unsigned short*)(w + HS_B);
    unsigned short* wtp = (unsigned short*)(w + WT_B);

    k_s1<<<SCB, 256, 0, stream>>>(src, dst, h, cntD, cntS, hs);
    k_scanA<<<2 * NB, 256, 0, stream>>>(cntD, cntS, totD, totS);
    k_scanB<<<1, 128, 0, stream>>>(totD, totS, baseD, baseS, rowp);
    k_s2<<<SCB, 256, 0, stream>>>(src, dst, W, cntD, cntS, baseD, baseS, pairs, srcv, wtp);
    k_fine<<<2 * NB, 256, 0, stream>>>(pairs, srcv, baseD, baseS, rowp, normdst, normsrc, csr);
    k_aggemm<<<NN / 16, 256, 0, stream>>>(hs, csr, rowp, normdst, normsrc, wtp, bias, out);
}